// Round 12
// baseline (234.188 us; speedup 1.0000x reference)
//
#include <hip/hip_runtime.h>
#include <hip/hip_bf16.h>

// ---------------------------------------------------------------------------
// 2-layer GraphConv (DGL norm='both') + mean_nodes pool + linear classifier.
// N=80000, E=1.28M, D=H=64, C=5, G=512.
// R11->R12: agg processes a CONTIGUOUS NODE PAIR (2n, 2n+1) per wave
// iteration. Pairs never straddle a 512-bucket, so the pair's edges are
// contiguous in col: ONE 64-lane col load covers both nodes, and each
// iteration issues 4 independent row loads feeding two separate accumulator
// sets -- two independent latency chains per wave (R11 had one), no extra
// VALU per edge. Per-node summation order is bitwise identical to R11, so
// absmax must stay exactly 4.882812e-4. Slow path for c0+c1>64 (P~3e-7).
// Rest identical to R11 (single-pass bucket CSR, MFMA gemm w/ epilogue).
// ---------------------------------------------------------------------------

#define NBK 160            // max buckets: ceil(80000/512)=157 <= 160
#define HB  256            // edge-pass blocks in pA
#define CAP 9216           // per-bucket slot capacity (mean 8192, +11 sigma)

typedef __attribute__((ext_vector_type(8))) short bf16x8;
typedef __attribute__((ext_vector_type(4))) float f32x4;

__device__ __forceinline__ float bflo(unsigned u) { return __uint_as_float(u << 16); }
__device__ __forceinline__ float bfhi(unsigned u) { return __uint_as_float(u & 0xffff0000u); }
__device__ __forceinline__ float bf1(unsigned short u) { return __uint_as_float((unsigned)u << 16); }
__device__ __forceinline__ unsigned short f2bf(float f) {   // RNE
    unsigned u = __float_as_uint(f);
    return (unsigned short)((u + 0x7fff + ((u >> 16) & 1)) >> 16);
}
__device__ __forceinline__ unsigned packbf(float lo, float hi) {
    return (unsigned)f2bf(lo) | ((unsigned)f2bf(hi) << 16);
}

// --- pA: single-pass bucket scatter (blocks < HB) + graph bounds (rest) ----
__global__ __launch_bounds__(256) void pA_scatter(
    const int* __restrict__ src, const int* __restrict__ dst,
    int* __restrict__ curD, int* __restrict__ curS,       // NBK cursors each, pre-zeroed
    int* __restrict__ pack, unsigned short* __restrict__ sloc,
    const int* __restrict__ gids, int* __restrict__ goffs,
    int E, int NB, int N, int G)
{
    if (blockIdx.x >= HB) {                  // fused bounds_kernel
        int i = (blockIdx.x - HB) * 256 + threadIdx.x;
        if (i >= N) return;
        int b = gids[i];
        if (i == 0) {
            for (int g = 0; g <= b; g++) goffs[g] = 0;
        } else {
            int a = gids[i - 1];
            for (int g = a + 1; g <= b; g++) goffs[g] = i;
        }
        if (i == N - 1) {
            for (int g = b + 1; g <= G; g++) goffs[g] = N;
        }
        return;
    }
    __shared__ int hd[NBK], hs[NBK];
    int t = threadIdx.x;
    for (int i = t; i < NB; i += 256) { hd[i] = 0; hs[i] = 0; }
    __syncthreads();
    int chunk = (E + HB - 1) / HB;
    int s0 = blockIdx.x * chunk, s1 = min(E, s0 + chunk);
    int q0 = s0 >> 2, q1 = s1 >> 2;          // s0 is 4-aligned (chunk%4==0)
    const int4* s4 = (const int4*)src;
    const int4* d4 = (const int4*)dst;
    for (int q = q0 + t; q < q1; q += 256) {
        int4 d = d4[q];
        int4 s = s4[q];
        atomicAdd(&hd[d.x >> 9], 1); atomicAdd(&hd[d.y >> 9], 1);
        atomicAdd(&hd[d.z >> 9], 1); atomicAdd(&hd[d.w >> 9], 1);
        atomicAdd(&hs[s.x >> 9], 1); atomicAdd(&hs[s.y >> 9], 1);
        atomicAdd(&hs[s.z >> 9], 1); atomicAdd(&hs[s.w >> 9], 1);
    }
    for (int i = (q1 << 2) + t; i < s1; i += 256) {   // tail
        atomicAdd(&hd[dst[i] >> 9], 1);
        atomicAdd(&hs[src[i] >> 9], 1);
    }
    __syncthreads();
    for (int b = t; b < NB; b += 256) {      // reserve global slots
        int cd = hd[b], cs = hs[b];
        hd[b] = cd ? atomicAdd(&curD[b], cd) : 0;   // device atomic, 1/bucket
        hs[b] = cs ? atomicAdd(&curS[b], cs) : 0;
    }
    __syncthreads();
    for (int q = q0 + t; q < q1; q += 256) { // chunk re-read is L2-hot
        int4 d = d4[q];
        int4 s = s4[q];
        #pragma unroll
        for (int j = 0; j < 4; j++) {
            int ss = j == 0 ? s.x : j == 1 ? s.y : j == 2 ? s.z : s.w;
            int dd = j == 0 ? d.x : j == 1 ? d.y : j == 2 ? d.z : d.w;
            int bd = dd >> 9, bs = ss >> 9;
            int pd = atomicAdd(&hd[bd], 1);  // LDS atomic
            int ps = atomicAdd(&hs[bs], 1);  // LDS atomic
            if (pd < CAP) pack[(size_t)bd * CAP + pd] = ((dd & 511) << 17) | ss;
            if (ps < CAP) sloc[(size_t)bs * CAP + ps] = (unsigned short)(ss & 511);
        }
    }
    for (int i = (q1 << 2) + t; i < s1; i += 256) {   // tail
        int s = src[i], d = dst[i];
        int bd = d >> 9, bs = s >> 9;
        int pd = atomicAdd(&hd[bd], 1);
        int ps = atomicAdd(&hs[bs], 1);
        if (pd < CAP) pack[(size_t)bd * CAP + pd] = ((d & 511) << 17) | s;
        if (ps < CAP) sloc[(size_t)bs * CAP + ps] = (unsigned short)(s & 511);
    }
}

// --- p5: dst mode -> CSR (row_offs,deg,col,ndst); src mode -> nsrc+prescale -
__global__ __launch_bounds__(256) void p5_build(
    const int* __restrict__ pack, const unsigned short* __restrict__ sloc,
    const int* __restrict__ curD, const int* __restrict__ curS,
    int* __restrict__ col, int* __restrict__ row_offs, int* __restrict__ deg,
    float* __restrict__ nsrc, float* __restrict__ ndst,
    const float* __restrict__ h, unsigned short* __restrict__ xs,
    int N, int NB)
{
    __shared__ int hist[512];
    __shared__ float nsl[512];
    __shared__ int wt[4];
    int t = threadIdx.x;
    bool dmode = blockIdx.x < NB;
    int b = dmode ? blockIdx.x : blockIdx.x - NB;
    int n0 = b << 9, n1 = min(N, n0 + 512);
    hist[t] = 0; hist[t + 256] = 0;
    __syncthreads();
    int e0 = b * CAP;
    int tot = min(dmode ? curD[b] : curS[b], CAP);
    int e1 = e0 + tot;
    if (!dmode) {
        for (int i = e0 + t; i < e1; i += 256)
            atomicAdd(&hist[sloc[i]], 1);            // LDS atomic
        __syncthreads();
        for (int n = n0 + t; n < n1; n += 256) {
            float s = rsqrtf((float)max(hist[n - n0], 1));
            nsrc[n] = s;
            nsl[n - n0] = s;
        }
        __syncthreads();
        int cnt = n1 - n0;
        const float2* h2p = (const float2*)h;
        ushort2* xp = (ushort2*)xs;
        for (int i = t; i < cnt * 32; i += 256) {
            int node = i >> 5;
            float s = nsl[node];
            float2 v = h2p[(size_t)(n0 + node) * 32 + (i & 31)];
            ushort2 o;
            o.x = f2bf(v.x * s);
            o.y = f2bf(v.y * s);
            xp[(size_t)(n0 + node) * 32 + (i & 31)] = o;
        }
        return;
    }
    for (int i = e0 + t; i < e1; i += 256)
        atomicAdd(&hist[pack[i] >> 17], 1);          // LDS atomic
    __syncthreads();
    int c0 = hist[2 * t], c1 = hist[2 * t + 1];
    int v = c0 + c1;
    int lane = t & 63, w = t >> 6;
    int x = v;
    #pragma unroll
    for (int off = 1; off < 64; off <<= 1) {
        int y = __shfl_up(x, off);
        if (lane >= off) x += y;
    }
    if (lane == 63) wt[w] = x;
    __syncthreads();
    int bw = 0;
    for (int i = 0; i < w; i++) bw += wt[i];
    int excl = x - v + bw;
    int n = n0 + 2 * t;
    if (n < n1) {
        row_offs[n] = e0 + excl;
        deg[n] = c0;
        ndst[n] = rsqrtf((float)max(c0, 1));
    }
    if (n + 1 < n1) {
        row_offs[n + 1] = e0 + excl + c0;
        deg[n + 1] = c1;
        ndst[n + 1] = rsqrtf((float)max(c1, 1));
    }
    hist[2 * t] = excl;
    hist[2 * t + 1] = excl + c0;
    __syncthreads();
    for (int i = e0 + t; i < e1; i += 256) {
        int wd = pack[i];
        int pos = atomicAdd(&hist[wd >> 17], 1);     // LDS atomic
        col[e0 + pos] = wd & 0x1FFFF;
    }
}

// --- gather-sum, contiguous node pair per wave iteration -------------------
// pair (2p, 2p+1): edges contiguous (row_offs[n+1]=row_offs[n]+deg[n] within
// bucket; pairs never straddle). One col load covers both; 4 independent row
// loads/iter feed two accumulator sets A (node0) and B (node1).
__global__ __launch_bounds__(256) void agg_kernel(
    const unsigned short* __restrict__ z, unsigned short* __restrict__ y,
    const int* __restrict__ col, const int* __restrict__ row_offs,
    const int* __restrict__ deg, int N)
{
    int lane = threadIdx.x & 63;
    int sub  = lane >> 3;
    int li   = lane & 7;
    const uint4* x4 = (const uint4*)z;

    int wid = (blockIdx.x * 256 + threadIdx.x) >> 6;
    int nw  = (gridDim.x * 256) >> 6;

    for (int pr = wid; 2 * pr < N; pr += nw) {
        int n0 = 2 * pr, n1 = n0 + 1;
        int ro0 = row_offs[n0];
        int c0  = deg[n0];
        int c1  = (n1 < N) ? deg[n1] : 0;
        int ctot = c0 + c1;
        float A[8], B[8];
        #pragma unroll
        for (int k = 0; k < 8; k++) { A[k] = 0.f; B[k] = 0.f; }

        if (ctot <= 64) {                    // fast path (P(miss) ~ 3e-7)
            int idx = 0;
            if (lane < ctot) idx = col[ro0 + lane];
            int cm0 = max(c0 - 1, 0), cm1 = max(c1 - 1, 0);
            int mx = max(c0, c1);
            for (int i = 0; i < mx; i += 16) {
                int e0 = i + sub, e1 = i + 8 + sub;
                int s0 = __shfl(idx, min(e0, cm0));
                int s1 = __shfl(idx, min(e1, cm0));
                int t0 = __shfl(idx, c0 + min(e0, cm1));
                int t1 = __shfl(idx, c0 + min(e1, cm1));
                uint4 v0 = make_uint4(0u,0u,0u,0u), v1 = v0, w0 = v0, w1 = v0;
                if (e0 < c0) v0 = x4[(size_t)s0 * 8 + li];
                if (e1 < c0) v1 = x4[(size_t)s1 * 8 + li];
                if (e0 < c1) w0 = x4[(size_t)t0 * 8 + li];
                if (e1 < c1) w1 = x4[(size_t)t1 * 8 + li];
                A[0] += bflo(v0.x); A[1] += bfhi(v0.x);
                A[2] += bflo(v0.y); A[3] += bfhi(v0.y);
                A[4] += bflo(v0.z); A[5] += bfhi(v0.z);
                A[6] += bflo(v0.w); A[7] += bfhi(v0.w);
                A[0] += bflo(v1.x); A[1] += bfhi(v1.x);
                A[2] += bflo(v1.y); A[3] += bfhi(v1.y);
                A[4] += bflo(v1.z); A[5] += bfhi(v1.z);
                A[6] += bflo(v1.w); A[7] += bfhi(v1.w);
                B[0] += bflo(w0.x); B[1] += bfhi(w0.x);
                B[2] += bflo(w0.y); B[3] += bfhi(w0.y);
                B[4] += bflo(w0.z); B[5] += bfhi(w0.z);
                B[6] += bflo(w0.w); B[7] += bfhi(w0.w);
                B[0] += bflo(w1.x); B[1] += bfhi(w1.x);
                B[2] += bflo(w1.y); B[3] += bfhi(w1.y);
                B[4] += bflo(w1.z); B[5] += bfhi(w1.z);
                B[6] += bflo(w1.w); B[7] += bfhi(w1.w);
            }
        } else {                             // rare slow path: per-node chunks
            #pragma unroll 1
            for (int nn = 0; nn < 2; nn++) {
                int cnt = nn ? c1 : c0;
                int ro  = nn ? ro0 + c0 : ro0;
                float T[8];
                #pragma unroll
                for (int k = 0; k < 8; k++) T[k] = 0.f;
                int cc = 0;
                while (cc < cnt) {
                    int m = min(cnt - cc, 64);
                    int cidx = (lane < m) ? col[ro + cc + lane] : 0;
                    for (int i = 0; i < m; i += 16) {
                        int e0 = i + sub, e1 = i + 8 + sub;
                        int s0 = __shfl(cidx, min(e0, m - 1));
                        int s1 = __shfl(cidx, min(e1, m - 1));
                        uint4 v0 = make_uint4(0u,0u,0u,0u), v1 = v0;
                        if (e0 < m) v0 = x4[(size_t)s0 * 8 + li];
                        if (e1 < m) v1 = x4[(size_t)s1 * 8 + li];
                        T[0] += bflo(v0.x); T[1] += bfhi(v0.x);
                        T[2] += bflo(v0.y); T[3] += bfhi(v0.y);
                        T[4] += bflo(v0.z); T[5] += bfhi(v0.z);
                        T[6] += bflo(v0.w); T[7] += bfhi(v0.w);
                        T[0] += bflo(v1.x); T[1] += bfhi(v1.x);
                        T[2] += bflo(v1.y); T[3] += bfhi(v1.y);
                        T[4] += bflo(v1.z); T[5] += bfhi(v1.z);
                        T[6] += bflo(v1.w); T[7] += bfhi(v1.w);
                    }
                    cc += 64;
                }
                #pragma unroll
                for (int k = 0; k < 8; k++) {
                    if (nn == 0) A[k] = T[k]; else B[k] = T[k];
                }
            }
        }

        #pragma unroll
        for (int off = 8; off <= 32; off <<= 1) {
            #pragma unroll
            for (int k = 0; k < 8; k++) {
                A[k] += __shfl_xor(A[k], off);
                B[k] += __shfl_xor(B[k], off);
            }
        }
        if (sub == 0) {                       // 8 lanes store node0's 128B row
            uint4 o;
            o.x = packbf(A[0], A[1]);
            o.y = packbf(A[2], A[3]);
            o.z = packbf(A[4], A[5]);
            o.w = packbf(A[6], A[7]);
            ((uint4*)y)[(size_t)n0 * 8 + li] = o;
        } else if (sub == 1 && n1 < N) {      // node1 in parallel
            uint4 o;
            o.x = packbf(B[0], B[1]);
            o.y = packbf(B[2], B[3]);
            o.z = packbf(B[4], B[5]);
            o.w = packbf(B[6], B[7]);
            ((uint4*)y)[(size_t)n1 * 8 + li] = o;
        }
    }
}

// --- GEMM + epilogue: Z[m] = relu(ndst[m]*(S[m]@W) + b) [* nsrc[m]] --------
__global__ __launch_bounds__(256) void gemm_kernel(
    const unsigned short* __restrict__ A, const float* __restrict__ W,
    const float* __restrict__ b, const float* __restrict__ ndst,
    const float* __restrict__ nsrc, unsigned short* __restrict__ Z,
    int M, int scale_out)
{
    int t = threadIdx.x, lane = t & 63, w = t >> 6;
    int col = lane & 15, quad = lane >> 4;
    bf16x8 bfrag[4][2];
    #pragma unroll
    for (int nt = 0; nt < 4; nt++)
        #pragma unroll
        for (int ks = 0; ks < 2; ks++)
            #pragma unroll
            for (int j = 0; j < 8; j++)
                bfrag[nt][ks][j] =
                    (short)f2bf(W[(ks * 32 + quad * 8 + j) * 64 + nt * 16 + col]);
    float bias[4];
    #pragma unroll
    for (int nt = 0; nt < 4; nt++) bias[nt] = b[nt * 16 + col];

    int mbase = blockIdx.x * 64 + w * 16;
    if (mbase >= M) return;
    int row = min(mbase + col, M - 1);
    const uint4* a4 = (const uint4*)A;
    union { uint4 u; bf16x8 v; } a0, a1;
    a0.u = a4[(size_t)row * 8 + quad];
    a1.u = a4[(size_t)row * 8 + 4 + quad];

    float nd[4], ns[4];
    #pragma unroll
    for (int r = 0; r < 4; r++) {
        int m = min(mbase + quad * 4 + r, M - 1);
        nd[r] = ndst[m];
        ns[r] = scale_out ? nsrc[m] : 1.f;
    }

    #pragma unroll
    for (int nt = 0; nt < 4; nt++) {
        f32x4 acc = {0.f, 0.f, 0.f, 0.f};
        acc = __builtin_amdgcn_mfma_f32_16x16x32_bf16(a0.v, bfrag[nt][0], acc, 0, 0, 0);
        acc = __builtin_amdgcn_mfma_f32_16x16x32_bf16(a1.v, bfrag[nt][1], acc, 0, 0, 0);
        #pragma unroll
        for (int r = 0; r < 4; r++) {
            int m = mbase + quad * 4 + r;
            if (m < M)
                Z[(size_t)m * 64 + nt * 16 + col] =
                    f2bf(fmaxf(nd[r] * acc[r] + bias[nt], 0.f) * ns[r]);
        }
    }
}

// --- per-graph mean pool + 64x5 classifier (block per graph) ---------------
__global__ __launch_bounds__(256) void pool_kernel(
    const unsigned short* __restrict__ h2, const int* __restrict__ goffs,
    const float* __restrict__ Wc, const float* __restrict__ bc,
    float* __restrict__ out)
{
    int g = blockIdx.x;
    int lane = threadIdx.x & 63;
    int w = threadIdx.x >> 6;
    int s = goffs[g], e = goffs[g + 1];
    float acc = 0.f;
    for (int i = s + w; i < e; i += 4) acc += bf1(h2[i * 64 + lane]);
    __shared__ float red[4][64];
    red[w][lane] = acc;
    __syncthreads();
    if (w == 0) {
        float tot = red[0][lane] + red[1][lane] + red[2][lane] + red[3][lane];
        float mean = tot / (float)max(e - s, 1);
        float wc[5];
        #pragma unroll
        for (int c = 0; c < 5; c++) wc[c] = Wc[lane * 5 + c];
        #pragma unroll
        for (int c = 0; c < 5; c++) {
            float p = mean * wc[c];
            #pragma unroll
            for (int off = 32; off; off >>= 1) p += __shfl_down(p, off);
            if (lane == 0) out[g * 5 + c] = p + bc[c];
        }
    }
}

extern "C" void kernel_launch(void* const* d_in, const int* in_sizes, int n_in,
                              void* d_out, int out_size, void* d_ws, size_t ws_size,
                              hipStream_t stream)
{
    const float* h    = (const float*)d_in[0];
    const int*   src  = (const int*)d_in[1];
    const int*   dst  = (const int*)d_in[2];
    const int*   gids = (const int*)d_in[3];
    const float* W1   = (const float*)d_in[4];
    const float* b1   = (const float*)d_in[5];
    const float* W2   = (const float*)d_in[6];
    const float* b2   = (const float*)d_in[7];
    const float* Wc   = (const float*)d_in[8];
    const float* bc   = (const float*)d_in[9];
    float* out = (float*)d_out;

    const int N = in_sizes[0] / 64;
    const int E = in_sizes[1];
    const int G = out_size / 5;
    const int NB = (N + 511) >> 9;
    const int NBB = (N + 255) / 256;        // bounds blocks

    auto align = [](size_t x) { return (x + 255) & ~(size_t)255; };
    char* p = (char*)d_ws;
    int* curD    = (int*)p;            p += align((size_t)2 * NBK * 4);
    int* curS    = curD + NBK;
    int* row_offs= (int*)p;            p += align((size_t)N * 4);
    int* deg     = (int*)p;            p += align((size_t)N * 4);
    float* nsrc  = (float*)p;          p += align((size_t)N * 4);
    float* ndst  = (float*)p;          p += align((size_t)N * 4);
    int* goffs   = (int*)p;            p += align((size_t)(G + 1) * 4);
    int* pack    = (int*)p;            p += align((size_t)NBK * CAP * 4);
    unsigned short* sloc = (unsigned short*)p; p += align((size_t)NBK * CAP * 2);
    int* col     = (int*)p;            p += align((size_t)NBK * CAP * 4);
    unsigned short* xs  = (unsigned short*)p; p += align((size_t)N * 64 * 2);
    unsigned short* s1  = (unsigned short*)p; p += align((size_t)N * 64 * 2);
    unsigned short* h1s = (unsigned short*)p; p += align((size_t)N * 64 * 2);
    unsigned short* s2  = s1;   // alias: s1 dead after gemm1
    unsigned short* h2  = xs;   // alias: xs dead after agg1

    hipMemsetAsync(curD, 0, (size_t)2 * NBK * 4, stream);

    pA_scatter<<<HB + NBB, 256, 0, stream>>>(src, dst, curD, curS, pack, sloc,
                                             gids, goffs, E, NB, N, G);
    p5_build<<<2 * NB, 256, 0, stream>>>(pack, sloc, curD, curS, col,
                                         row_offs, deg, nsrc, ndst, h, xs, N, NB);

    agg_kernel<<<4096, 256, 0, stream>>>(xs, s1, col, row_offs, deg, N);
    gemm_kernel<<<(N + 63) / 64, 256, 0, stream>>>(s1, W1, b1, ndst, nsrc,
                                                   h1s, N, 1);
    agg_kernel<<<4096, 256, 0, stream>>>(h1s, s2, col, row_offs, deg, N);
    gemm_kernel<<<(N + 63) / 64, 256, 0, stream>>>(s2, W2, b2, ndst, nsrc,
                                                   h2, N, 0);

    pool_kernel<<<G, 256, 0, stream>>>(h2, goffs, Wc, bc, out);
}

// Round 13
// 224.854 us; speedup vs baseline: 1.0415x; 1.0415x over previous
//
#include <hip/hip_runtime.h>
#include <hip/hip_bf16.h>

// ---------------------------------------------------------------------------
// 2-layer GraphConv (DGL norm='both') + mean_nodes pool + linear classifier.
// N=80000, E=1.28M, D=H=64, C=5, G=512.
// R12->R13: revert to R11 (best, 223.9us). R12's node-pair agg regressed
// (+10us): doubled xor-reduce VALU + extra shfls/guards + lost col prefetch,
// while memory rounds/iteration stayed the same. agg evidence across R7/R9/
// R11/R12: in-wave ILP doesn't move it; resident-wave count does. Single
// change vs R11: __launch_bounds__(256,8) on agg (VGPR ~56 -> cap 64 safe)
// to raise the resident-wave ceiling.
// ---------------------------------------------------------------------------

#define NBK 160            // max buckets: ceil(80000/512)=157 <= 160
#define HB  256            // edge-pass blocks in pA
#define CAP 9216           // per-bucket slot capacity (mean 8192, +11 sigma)

typedef __attribute__((ext_vector_type(8))) short bf16x8;
typedef __attribute__((ext_vector_type(4))) float f32x4;

__device__ __forceinline__ float bflo(unsigned u) { return __uint_as_float(u << 16); }
__device__ __forceinline__ float bfhi(unsigned u) { return __uint_as_float(u & 0xffff0000u); }
__device__ __forceinline__ float bf1(unsigned short u) { return __uint_as_float((unsigned)u << 16); }
__device__ __forceinline__ unsigned short f2bf(float f) {   // RNE
    unsigned u = __float_as_uint(f);
    return (unsigned short)((u + 0x7fff + ((u >> 16) & 1)) >> 16);
}
__device__ __forceinline__ unsigned packbf(float lo, float hi) {
    return (unsigned)f2bf(lo) | ((unsigned)f2bf(hi) << 16);
}

// --- pA: single-pass bucket scatter (blocks < HB) + graph bounds (rest) ----
__global__ __launch_bounds__(256) void pA_scatter(
    const int* __restrict__ src, const int* __restrict__ dst,
    int* __restrict__ curD, int* __restrict__ curS,       // NBK cursors each, pre-zeroed
    int* __restrict__ pack, unsigned short* __restrict__ sloc,
    const int* __restrict__ gids, int* __restrict__ goffs,
    int E, int NB, int N, int G)
{
    if (blockIdx.x >= HB) {                  // fused bounds_kernel
        int i = (blockIdx.x - HB) * 256 + threadIdx.x;
        if (i >= N) return;
        int b = gids[i];
        if (i == 0) {
            for (int g = 0; g <= b; g++) goffs[g] = 0;
        } else {
            int a = gids[i - 1];
            for (int g = a + 1; g <= b; g++) goffs[g] = i;
        }
        if (i == N - 1) {
            for (int g = b + 1; g <= G; g++) goffs[g] = N;
        }
        return;
    }
    __shared__ int hd[NBK], hs[NBK];
    int t = threadIdx.x;
    for (int i = t; i < NB; i += 256) { hd[i] = 0; hs[i] = 0; }
    __syncthreads();
    int chunk = (E + HB - 1) / HB;
    int s0 = blockIdx.x * chunk, s1 = min(E, s0 + chunk);
    int q0 = s0 >> 2, q1 = s1 >> 2;          // s0 is 4-aligned (chunk%4==0)
    const int4* s4 = (const int4*)src;
    const int4* d4 = (const int4*)dst;
    for (int q = q0 + t; q < q1; q += 256) {
        int4 d = d4[q];
        int4 s = s4[q];
        atomicAdd(&hd[d.x >> 9], 1); atomicAdd(&hd[d.y >> 9], 1);
        atomicAdd(&hd[d.z >> 9], 1); atomicAdd(&hd[d.w >> 9], 1);
        atomicAdd(&hs[s.x >> 9], 1); atomicAdd(&hs[s.y >> 9], 1);
        atomicAdd(&hs[s.z >> 9], 1); atomicAdd(&hs[s.w >> 9], 1);
    }
    for (int i = (q1 << 2) + t; i < s1; i += 256) {   // tail
        atomicAdd(&hd[dst[i] >> 9], 1);
        atomicAdd(&hs[src[i] >> 9], 1);
    }
    __syncthreads();
    for (int b = t; b < NB; b += 256) {      // reserve global slots
        int cd = hd[b], cs = hs[b];
        hd[b] = cd ? atomicAdd(&curD[b], cd) : 0;   // device atomic, 1/bucket
        hs[b] = cs ? atomicAdd(&curS[b], cs) : 0;
    }
    __syncthreads();
    for (int q = q0 + t; q < q1; q += 256) { // chunk re-read is L2-hot
        int4 d = d4[q];
        int4 s = s4[q];
        #pragma unroll
        for (int j = 0; j < 4; j++) {
            int ss = j == 0 ? s.x : j == 1 ? s.y : j == 2 ? s.z : s.w;
            int dd = j == 0 ? d.x : j == 1 ? d.y : j == 2 ? d.z : d.w;
            int bd = dd >> 9, bs = ss >> 9;
            int pd = atomicAdd(&hd[bd], 1);  // LDS atomic
            int ps = atomicAdd(&hs[bs], 1);  // LDS atomic
            if (pd < CAP) pack[(size_t)bd * CAP + pd] = ((dd & 511) << 17) | ss;
            if (ps < CAP) sloc[(size_t)bs * CAP + ps] = (unsigned short)(ss & 511);
        }
    }
    for (int i = (q1 << 2) + t; i < s1; i += 256) {   // tail
        int s = src[i], d = dst[i];
        int bd = d >> 9, bs = s >> 9;
        int pd = atomicAdd(&hd[bd], 1);
        int ps = atomicAdd(&hs[bs], 1);
        if (pd < CAP) pack[(size_t)bd * CAP + pd] = ((d & 511) << 17) | s;
        if (ps < CAP) sloc[(size_t)bs * CAP + ps] = (unsigned short)(s & 511);
    }
}

// --- p5: dst mode -> CSR (row_offs,deg,col,ndst); src mode -> nsrc+prescale -
__global__ __launch_bounds__(256) void p5_build(
    const int* __restrict__ pack, const unsigned short* __restrict__ sloc,
    const int* __restrict__ curD, const int* __restrict__ curS,
    int* __restrict__ col, int* __restrict__ row_offs, int* __restrict__ deg,
    float* __restrict__ nsrc, float* __restrict__ ndst,
    const float* __restrict__ h, unsigned short* __restrict__ xs,
    int N, int NB)
{
    __shared__ int hist[512];
    __shared__ float nsl[512];
    __shared__ int wt[4];
    int t = threadIdx.x;
    bool dmode = blockIdx.x < NB;
    int b = dmode ? blockIdx.x : blockIdx.x - NB;
    int n0 = b << 9, n1 = min(N, n0 + 512);
    hist[t] = 0; hist[t + 256] = 0;
    __syncthreads();
    int e0 = b * CAP;
    int tot = min(dmode ? curD[b] : curS[b], CAP);
    int e1 = e0 + tot;
    if (!dmode) {
        for (int i = e0 + t; i < e1; i += 256)
            atomicAdd(&hist[sloc[i]], 1);            // LDS atomic
        __syncthreads();
        for (int n = n0 + t; n < n1; n += 256) {
            float s = rsqrtf((float)max(hist[n - n0], 1));
            nsrc[n] = s;
            nsl[n - n0] = s;
        }
        __syncthreads();
        int cnt = n1 - n0;
        const float2* h2p = (const float2*)h;
        ushort2* xp = (ushort2*)xs;
        for (int i = t; i < cnt * 32; i += 256) {
            int node = i >> 5;
            float s = nsl[node];
            float2 v = h2p[(size_t)(n0 + node) * 32 + (i & 31)];
            ushort2 o;
            o.x = f2bf(v.x * s);
            o.y = f2bf(v.y * s);
            xp[(size_t)(n0 + node) * 32 + (i & 31)] = o;
        }
        return;
    }
    for (int i = e0 + t; i < e1; i += 256)
        atomicAdd(&hist[pack[i] >> 17], 1);          // LDS atomic
    __syncthreads();
    int c0 = hist[2 * t], c1 = hist[2 * t + 1];
    int v = c0 + c1;
    int lane = t & 63, w = t >> 6;
    int x = v;
    #pragma unroll
    for (int off = 1; off < 64; off <<= 1) {
        int y = __shfl_up(x, off);
        if (lane >= off) x += y;
    }
    if (lane == 63) wt[w] = x;
    __syncthreads();
    int bw = 0;
    for (int i = 0; i < w; i++) bw += wt[i];
    int excl = x - v + bw;
    int n = n0 + 2 * t;
    if (n < n1) {
        row_offs[n] = e0 + excl;
        deg[n] = c0;
        ndst[n] = rsqrtf((float)max(c0, 1));
    }
    if (n + 1 < n1) {
        row_offs[n + 1] = e0 + excl + c0;
        deg[n + 1] = c1;
        ndst[n + 1] = rsqrtf((float)max(c1, 1));
    }
    hist[2 * t] = excl;
    hist[2 * t + 1] = excl + c0;
    __syncthreads();
    for (int i = e0 + t; i < e1; i += 256) {
        int wd = pack[i];
        int pos = atomicAdd(&hist[wd >> 17], 1);     // LDS atomic
        col[e0 + pos] = wd & 0x1FFFF;
    }
}

// --- pure gather-sum with next-node prefetch -------------------------------
__global__ __launch_bounds__(256, 8) void agg_kernel(
    const unsigned short* __restrict__ z, unsigned short* __restrict__ y,
    const int* __restrict__ col, const int* __restrict__ row_offs,
    const int* __restrict__ deg, int N)
{
    int lane = threadIdx.x & 63;
    int sub  = lane >> 3;
    int li   = lane & 7;
    const uint4* x4 = (const uint4*)z;

    int wid = (blockIdx.x * 256 + threadIdx.x) >> 6;
    int nw  = (gridDim.x * 256) >> 6;

    int ro = 0, cnt = 0, idx = 0;
    if (wid < N) {
        ro = row_offs[wid];
        cnt = deg[wid];
        if (lane < min(cnt, 64)) idx = col[ro + lane];
    }
    for (int node = wid; node < N; node += nw) {
        int nnode = node + nw;
        int nro = 0, ncnt = 0;
        if (nnode < N) { nro = row_offs[nnode]; ncnt = deg[nnode]; }  // prefetch

        float a0=0.f,a1=0.f,a2=0.f,a3=0.f,a4=0.f,a5=0.f,a6=0.f,a7=0.f;
        int cc = 0;
        int cidx = idx;
        while (cc < cnt) {
            int m = min(cnt - cc, 64);
            for (int i = 0; i < m; i += 32) {
                int e1 = i + sub, e2 = i + 8 + sub, e3 = i + 16 + sub, e4 = i + 24 + sub;
                int s1 = __shfl(cidx, min(e1, m - 1));
                int s2 = __shfl(cidx, min(e2, m - 1));
                int s3 = __shfl(cidx, min(e3, m - 1));
                int s4 = __shfl(cidx, min(e4, m - 1));
                uint4 v1 = make_uint4(0u,0u,0u,0u), v2 = v1, v3 = v1, v4 = v1;
                if (e1 < m) v1 = x4[(size_t)s1 * 8 + li];
                if (e2 < m) v2 = x4[(size_t)s2 * 8 + li];
                if (e3 < m) v3 = x4[(size_t)s3 * 8 + li];
                if (e4 < m) v4 = x4[(size_t)s4 * 8 + li];
                a0 += bflo(v1.x); a1 += bfhi(v1.x);
                a2 += bflo(v1.y); a3 += bfhi(v1.y);
                a4 += bflo(v1.z); a5 += bfhi(v1.z);
                a6 += bflo(v1.w); a7 += bfhi(v1.w);
                a0 += bflo(v2.x); a1 += bfhi(v2.x);
                a2 += bflo(v2.y); a3 += bfhi(v2.y);
                a4 += bflo(v2.z); a5 += bfhi(v2.z);
                a6 += bflo(v2.w); a7 += bfhi(v2.w);
                a0 += bflo(v3.x); a1 += bfhi(v3.x);
                a2 += bflo(v3.y); a3 += bfhi(v3.y);
                a4 += bflo(v3.z); a5 += bfhi(v3.z);
                a6 += bflo(v3.w); a7 += bfhi(v3.w);
                a0 += bflo(v4.x); a1 += bfhi(v4.x);
                a2 += bflo(v4.y); a3 += bfhi(v4.y);
                a4 += bflo(v4.z); a5 += bfhi(v4.z);
                a6 += bflo(v4.w); a7 += bfhi(v4.w);
            }
            cc += 64;
            if (cc < cnt) cidx = (lane < min(cnt - cc, 64)) ? col[ro + cc + lane] : 0;
        }
        // prefetch next node's col during the reduce
        idx = 0;
        if (nnode < N && lane < min(ncnt, 64)) idx = col[nro + lane];

        #pragma unroll
        for (int off = 8; off <= 32; off <<= 1) {
            a0 += __shfl_xor(a0, off); a1 += __shfl_xor(a1, off);
            a2 += __shfl_xor(a2, off); a3 += __shfl_xor(a3, off);
            a4 += __shfl_xor(a4, off); a5 += __shfl_xor(a5, off);
            a6 += __shfl_xor(a6, off); a7 += __shfl_xor(a7, off);
        }
        if (sub == 0) {                       // 8 lanes store the 128B row
            uint4 o;
            o.x = packbf(a0, a1);
            o.y = packbf(a2, a3);
            o.z = packbf(a4, a5);
            o.w = packbf(a6, a7);
            ((uint4*)y)[(size_t)node * 8 + li] = o;
        }
        ro = nro; cnt = ncnt;
    }
}

// --- GEMM + epilogue: Z[m] = relu(ndst[m]*(S[m]@W) + b) [* nsrc[m]] --------
__global__ __launch_bounds__(256) void gemm_kernel(
    const unsigned short* __restrict__ A, const float* __restrict__ W,
    const float* __restrict__ b, const float* __restrict__ ndst,
    const float* __restrict__ nsrc, unsigned short* __restrict__ Z,
    int M, int scale_out)
{
    int t = threadIdx.x, lane = t & 63, w = t >> 6;
    int col = lane & 15, quad = lane >> 4;
    bf16x8 bfrag[4][2];
    #pragma unroll
    for (int nt = 0; nt < 4; nt++)
        #pragma unroll
        for (int ks = 0; ks < 2; ks++)
            #pragma unroll
            for (int j = 0; j < 8; j++)
                bfrag[nt][ks][j] =
                    (short)f2bf(W[(ks * 32 + quad * 8 + j) * 64 + nt * 16 + col]);
    float bias[4];
    #pragma unroll
    for (int nt = 0; nt < 4; nt++) bias[nt] = b[nt * 16 + col];

    int mbase = blockIdx.x * 64 + w * 16;
    if (mbase >= M) return;
    int row = min(mbase + col, M - 1);
    const uint4* a4 = (const uint4*)A;
    union { uint4 u; bf16x8 v; } a0, a1;
    a0.u = a4[(size_t)row * 8 + quad];
    a1.u = a4[(size_t)row * 8 + 4 + quad];

    float nd[4], ns[4];
    #pragma unroll
    for (int r = 0; r < 4; r++) {
        int m = min(mbase + quad * 4 + r, M - 1);
        nd[r] = ndst[m];
        ns[r] = scale_out ? nsrc[m] : 1.f;
    }

    #pragma unroll
    for (int nt = 0; nt < 4; nt++) {
        f32x4 acc = {0.f, 0.f, 0.f, 0.f};
        acc = __builtin_amdgcn_mfma_f32_16x16x32_bf16(a0.v, bfrag[nt][0], acc, 0, 0, 0);
        acc = __builtin_amdgcn_mfma_f32_16x16x32_bf16(a1.v, bfrag[nt][1], acc, 0, 0, 0);
        #pragma unroll
        for (int r = 0; r < 4; r++) {
            int m = mbase + quad * 4 + r;
            if (m < M)
                Z[(size_t)m * 64 + nt * 16 + col] =
                    f2bf(fmaxf(nd[r] * acc[r] + bias[nt], 0.f) * ns[r]);
        }
    }
}

// --- per-graph mean pool + 64x5 classifier (block per graph) ---------------
__global__ __launch_bounds__(256) void pool_kernel(
    const unsigned short* __restrict__ h2, const int* __restrict__ goffs,
    const float* __restrict__ Wc, const float* __restrict__ bc,
    float* __restrict__ out)
{
    int g = blockIdx.x;
    int lane = threadIdx.x & 63;
    int w = threadIdx.x >> 6;
    int s = goffs[g], e = goffs[g + 1];
    float acc = 0.f;
    for (int i = s + w; i < e; i += 4) acc += bf1(h2[i * 64 + lane]);
    __shared__ float red[4][64];
    red[w][lane] = acc;
    __syncthreads();
    if (w == 0) {
        float tot = red[0][lane] + red[1][lane] + red[2][lane] + red[3][lane];
        float mean = tot / (float)max(e - s, 1);
        float wc[5];
        #pragma unroll
        for (int c = 0; c < 5; c++) wc[c] = Wc[lane * 5 + c];
        #pragma unroll
        for (int c = 0; c < 5; c++) {
            float p = mean * wc[c];
            #pragma unroll
            for (int off = 32; off; off >>= 1) p += __shfl_down(p, off);
            if (lane == 0) out[g * 5 + c] = p + bc[c];
        }
    }
}

extern "C" void kernel_launch(void* const* d_in, const int* in_sizes, int n_in,
                              void* d_out, int out_size, void* d_ws, size_t ws_size,
                              hipStream_t stream)
{
    const float* h    = (const float*)d_in[0];
    const int*   src  = (const int*)d_in[1];
    const int*   dst  = (const int*)d_in[2];
    const int*   gids = (const int*)d_in[3];
    const float* W1   = (const float*)d_in[4];
    const float* b1   = (const float*)d_in[5];
    const float* W2   = (const float*)d_in[6];
    const float* b2   = (const float*)d_in[7];
    const float* Wc   = (const float*)d_in[8];
    const float* bc   = (const float*)d_in[9];
    float* out = (float*)d_out;

    const int N = in_sizes[0] / 64;
    const int E = in_sizes[1];
    const int G = out_size / 5;
    const int NB = (N + 511) >> 9;
    const int NBB = (N + 255) / 256;        // bounds blocks

    auto align = [](size_t x) { return (x + 255) & ~(size_t)255; };
    char* p = (char*)d_ws;
    int* curD    = (int*)p;            p += align((size_t)2 * NBK * 4);
    int* curS    = curD + NBK;
    int* row_offs= (int*)p;            p += align((size_t)N * 4);
    int* deg     = (int*)p;            p += align((size_t)N * 4);
    float* nsrc  = (float*)p;          p += align((size_t)N * 4);
    float* ndst  = (float*)p;          p += align((size_t)N * 4);
    int* goffs   = (int*)p;            p += align((size_t)(G + 1) * 4);
    int* pack    = (int*)p;            p += align((size_t)NBK * CAP * 4);
    unsigned short* sloc = (unsigned short*)p; p += align((size_t)NBK * CAP * 2);
    int* col     = (int*)p;            p += align((size_t)NBK * CAP * 4);
    unsigned short* xs  = (unsigned short*)p; p += align((size_t)N * 64 * 2);
    unsigned short* s1  = (unsigned short*)p; p += align((size_t)N * 64 * 2);
    unsigned short* h1s = (unsigned short*)p; p += align((size_t)N * 64 * 2);
    unsigned short* s2  = s1;   // alias: s1 dead after gemm1
    unsigned short* h2  = xs;   // alias: xs dead after agg1

    hipMemsetAsync(curD, 0, (size_t)2 * NBK * 4, stream);

    pA_scatter<<<HB + NBB, 256, 0, stream>>>(src, dst, curD, curS, pack, sloc,
                                             gids, goffs, E, NB, N, G);
    p5_build<<<2 * NB, 256, 0, stream>>>(pack, sloc, curD, curS, col,
                                         row_offs, deg, nsrc, ndst, h, xs, N, NB);

    agg_kernel<<<4096, 256, 0, stream>>>(xs, s1, col, row_offs, deg, N);
    gemm_kernel<<<(N + 63) / 64, 256, 0, stream>>>(s1, W1, b1, ndst, nsrc,
                                                   h1s, N, 1);
    agg_kernel<<<4096, 256, 0, stream>>>(h1s, s2, col, row_offs, deg, N);
    gemm_kernel<<<(N + 63) / 64, 256, 0, stream>>>(s2, W2, b2, ndst, nsrc,
                                                   h2, N, 0);

    pool_kernel<<<G, 256, 0, stream>>>(h2, goffs, Wc, bc, out);
}